// Round 8
// baseline (165.796 us; speedup 1.0000x reference)
//
#include <hip/hip_runtime.h>
#include <cstddef>

// QuadTree attention, 3 levels. B=4, C=128, NHEAD=8, d=16.
// Grids: 16x16 (S=256), 32x32 (S=1024), 64x64 (S=4096). TOPKS=(16,8,8).
//
// R8: software-pipelined gather walls. (1) lvl1 K gather issued before the
// msg0 loop (latency hidden under 64 FMAs); (2) stage F: GT for all 4
// parents up front, 2 score passes into disjoint LDS regions, then both
// msg halves unrolled against stable LDS so V-gathers form one wall.

#define DPP_QUAD_X1 0xB1
#define DPP_QUAD_X2 0x4E
#define DPP_ROR_1   0x121
#define DPP_ROR_2   0x122
#define DPP_ROR_4   0x124
#define DPP_ROR_8   0x128

template<int C>
__device__ __forceinline__ int dpp_i(int x) {
    return __builtin_amdgcn_mov_dpp(x, C, 0xF, 0xF, true);
}
template<int C>
__device__ __forceinline__ float dpp_f(float x) {
    return __int_as_float(__builtin_amdgcn_mov_dpp(__float_as_int(x), C, 0xF, 0xF, true));
}
__device__ __forceinline__ float rowmax16(float x) {
    x = fmaxf(x, dpp_f<DPP_ROR_1>(x));
    x = fmaxf(x, dpp_f<DPP_ROR_2>(x));
    x = fmaxf(x, dpp_f<DPP_ROR_4>(x));
    x = fmaxf(x, dpp_f<DPP_ROR_8>(x));
    return x;
}
__device__ __forceinline__ int rowmin16i(int x) {
    { int o = dpp_i<DPP_ROR_1>(x); x = o < x ? o : x; }
    { int o = dpp_i<DPP_ROR_2>(x); x = o < x ? o : x; }
    { int o = dpp_i<DPP_ROR_4>(x); x = o < x ? o : x; }
    { int o = dpp_i<DPP_ROR_8>(x); x = o < x ? o : x; }
    return x;
}
__device__ __forceinline__ float quadmax4(float x) {
    x = fmaxf(x, dpp_f<DPP_QUAD_X1>(x));
    x = fmaxf(x, dpp_f<DPP_QUAD_X2>(x));
    return x;
}
__device__ __forceinline__ float quadsum4(float x) {
    x += dpp_f<DPP_QUAD_X1>(x);
    x += dpp_f<DPP_QUAD_X2>(x);
    return x;
}
__device__ __forceinline__ float wavemax(float x) {
    x = rowmax16(x);
    x = fmaxf(x, __shfl_xor(x, 16));
    x = fmaxf(x, __shfl_xor(x, 32));
    return x;
}
__device__ __forceinline__ float wavesum(float x) {
    x += dpp_f<DPP_ROR_1>(x); x += dpp_f<DPP_ROR_2>(x);
    x += dpp_f<DPP_ROR_4>(x); x += dpp_f<DPP_ROR_8>(x);
    x += __shfl_xor(x, 16);   x += __shfl_xor(x, 32);
    return x;
}
__device__ __forceinline__ float dot16(const float* __restrict__ qp, const float* kr) {
    float s = 0.f;
    #pragma unroll
    for (int i = 0; i < 4; ++i) {
        float4 a = *(const float4*)(qp + i*4);
        s = fmaf(a.x, kr[i*4+0], s);
        s = fmaf(a.y, kr[i*4+1], s);
        s = fmaf(a.z, kr[i*4+2], s);
        s = fmaf(a.w, kr[i*4+3], s);
    }
    return s;
}
__device__ __forceinline__ int child32(int s, int c) {
    return (((s >> 4)*2 + (c >> 1)) << 5) + ((s & 15)*2 + (c & 1));
}
__device__ __forceinline__ int child64(int g, int c) {
    return (((g >> 5)*2 + (c >> 1)) << 6) + ((g & 31)*2 + (c & 1));
}

// arena layout (floats per wave)
// 0..271   : lvl0 padded-p (B/C) -> lvl2 scores overlay (F)
// 288..559 : lvl1 p [4][68] (D/E) -> lvl2 scores overlay (F)
//            lvl2 score base for t1: (t1>>1)*288 + (t1&1)*144 (max idx 571)
#define W0V  560   // lvl0 winner values [16]   (dead after D -> overlaid by F scores tail)
#define W0P  576   // lvl0 winner pos    [16]
#define MSG0 592   // [16]
#define MSG1 608   // [4][16]
#define W1V  672   // lvl1 winner values [4][8]
#define W1P  704   // lvl1 winner g1     [4][8]
#define GT   736   // child-index table  [128] (lvl1 uses 0..63, lvl2 all 128)
#define OUTT 864   // out tile [16][16]
#define ARENA 1120

// ---------------- Repack: head-major Q + KV-interleaved ----------------
__global__ __launch_bounds__(256) void k_repack(
    const float* __restrict__ q1, const float* __restrict__ k1, const float* __restrict__ v1,
    const float* __restrict__ q2, const float* __restrict__ k2, const float* __restrict__ v2,
    float* __restrict__ Q1h, float* __restrict__ KV1,
    float* __restrict__ Q2h, float* __restrict__ KV2)
{
    const int x = blockIdx.x, n = blockIdx.y, b = blockIdx.z;
    const int t = threadIdx.x;
    __shared__ float tA[16][129];
    __shared__ float tB[16][129];

    if (x < 20) {
        const float* src; float* dst; int S, ck;
        if (x < 4) { src = q1; dst = Q1h; S = 1024; ck = x; }
        else       { src = q2; dst = Q2h; S = 4096; ck = x - 4; }
        const int tok0 = ck * 256;
        const float* sp = src + ((size_t)(b*128 + n*16))*S + tok0;
        const int col = t & 127, half = t >> 7;
        #pragma unroll
        for (int j = 0; j < 8; ++j) {
            const int row = j*2 + half;
            tA[row][col] = sp[(size_t)row*S + col];
            tB[row][col] = sp[(size_t)row*S + col + 128];
        }
        __syncthreads();
        float* dp = dst + ((size_t)((b*8 + n)*S) + tok0 + t)*16;
        #pragma unroll
        for (int i = 0; i < 4; ++i) {
            float4 o;
            o.x = (half ? tB : tA)[i*4+0][col];
            o.y = (half ? tB : tA)[i*4+1][col];
            o.z = (half ? tB : tA)[i*4+2][col];
            o.w = (half ? tB : tA)[i*4+3][col];
            *(float4*)(dp + i*4) = o;
        }
    } else {
        const float* sK; const float* sV; float* dst; int S, ck;
        if (x < 28) { sK = k1; sV = v1; dst = KV1; S = 1024; ck = x - 20; }
        else        { sK = k2; sV = v2; dst = KV2; S = 4096; ck = x - 28; }
        const int tok0 = ck * 128;
        const int col = t & 127, rp = t >> 7;
        const float* kp = sK + ((size_t)(b*128 + n*16))*S + tok0;
        const float* vp = sV + ((size_t)(b*128 + n*16))*S + tok0;
        #pragma unroll
        for (int j = 0; j < 8; ++j) {
            const int row = j*2 + rp;
            tA[row][col] = kp[(size_t)row*S + col];
            tB[row][col] = vp[(size_t)row*S + col];
        }
        __syncthreads();
        const int tok = t >> 1, half = t & 1;
        float* dp = dst + (((size_t)((b*8 + n)*S) + tok0 + tok))*32 + half*16;
        #pragma unroll
        for (int i = 0; i < 4; ++i) {
            float4 o;
            o.x = (half ? tB : tA)[i*4+0][tok];
            o.y = (half ? tB : tA)[i*4+1][tok];
            o.z = (half ? tB : tA)[i*4+2][tok];
            o.w = (half ? tB : tA)[i*4+3][tok];
            *(float4*)(dp + i*4) = o;
        }
    }
}

// ---------------- Fused 3-level subtree kernel ----------------
__global__ __launch_bounds__(256) void k_fused(
    const float* __restrict__ q0, const float* __restrict__ k0, const float* __restrict__ v0,
    const float* __restrict__ Q1h, const float* __restrict__ KV1,
    const float* __restrict__ Q2h, const float* __restrict__ KV2,
    float* __restrict__ out)
{
    const int tid = threadIdx.x, lane = tid & 63, wid = tid >> 6;
    const int id  = blockIdx.x;
    const int b   = id & 3;
    const int hh  = (id >> 2) & 1;
    const int loc = id >> 3;
    const int l0  = hh*128 + (loc & 127);
    const int n   = (loc >> 7)*4 + wid;
    const int H0 = l0 >> 4, W0 = l0 & 15;

    __shared__ float arenaAll[4][ARENA];
    float* A = arenaAll[wid];

    const float* Q1hh = Q1h + (size_t)((b*8 + n)*1024)*16;
    const float* KV1h = KV1 + (size_t)((b*8 + n)*1024)*32;
    const float* Q2hh = Q2h + (size_t)((b*8 + n)*4096)*16;
    const float* KV2h = KV2 + (size_t)((b*8 + n)*4096)*32;

    // ======== stage A: lvl0 scores + wave softmax ========
    const float* qb = q0 + ((size_t)(b*128 + n*16))*256 + l0;
    const float* kb = k0 + ((size_t)(b*128 + n*16))*256 + lane*4;
    float qreg[16];
    #pragma unroll
    for (int dd = 0; dd < 16; ++dd) qreg[dd] = qb[(size_t)dd*256];
    float p[4] = {0.f, 0.f, 0.f, 0.f};
    #pragma unroll
    for (int dd = 0; dd < 16; ++dd) {
        float4 kv = *(const float4*)(kb + (size_t)dd*256);
        p[0] = fmaf(qreg[dd], kv.x, p[0]);
        p[1] = fmaf(qreg[dd], kv.y, p[1]);
        p[2] = fmaf(qreg[dd], kv.z, p[2]);
        p[3] = fmaf(qreg[dd], kv.w, p[3]);
    }
    #pragma unroll
    for (int j = 0; j < 4; ++j) p[j] *= 0.25f;
    float m = fmaxf(fmaxf(p[0], p[1]), fmaxf(p[2], p[3]));
    m = wavemax(m);
    float ls = 0.f;
    #pragma unroll
    for (int j = 0; j < 4; ++j) { p[j] = expf(p[j] - m); ls += p[j]; }
    const float inv = 1.f / wavesum(ls);
    #pragma unroll
    for (int j = 0; j < 4; ++j) p[j] *= inv;

    const int li = lane & 15;

    // ======== stage B: top-16 of 256 ========
    float w0 = p[0], w1 = p[1], w2 = p[2], w3 = p[3];
    float cv = 0.f; int cpos = 0;
    #pragma unroll 1
    for (int it = 0; it < 16; ++it) {
        float bv = fmaxf(fmaxf(w0, w1), fmaxf(w2, w3));
        bv = rowmax16(bv);
        int cs = 0x7FFFFFFF;
        cs = (w3 == bv) ? (lane*4 + 3) : cs;
        cs = (w2 == bv) ? (lane*4 + 2) : cs;
        cs = (w1 == bv) ? (lane*4 + 1) : cs;
        cs = (w0 == bv) ? (lane*4 + 0) : cs;
        cs = rowmin16i(cs);
        w0 = (cs == lane*4 + 0) ? 0.f : w0;
        w1 = (cs == lane*4 + 1) ? 0.f : w1;
        w2 = (cs == lane*4 + 2) ? 0.f : w2;
        w3 = (cs == lane*4 + 3) ? 0.f : w3;
        if (li == it) { cv = bv; cpos = cs; }
    }
    // rank merge of 64 candidates
    A[lane]      = cv;
    A[64 + lane] = __int_as_float(cpos);
    *(float4*)&A[288 + lane*4] = make_float4(0.f, 0.f, 0.f, 0.f);   // clear flags
    int rank = 0;
    #pragma unroll
    for (int jj = 0; jj < 16; ++jj) {
        float4 vv = *(const float4*)&A[jj*4];
        float4 pw = *(const float4*)&A[64 + jj*4];
        const int p0i = __float_as_int(pw.x), p1i = __float_as_int(pw.y);
        const int p2i = __float_as_int(pw.z), p3i = __float_as_int(pw.w);
        rank += (vv.x > cv || (vv.x == cv && p0i < cpos)) ? 1 : 0;
        rank += (vv.y > cv || (vv.y == cv && p1i < cpos)) ? 1 : 0;
        rank += (vv.z > cv || (vv.z == cv && p2i < cpos)) ? 1 : 0;
        rank += (vv.w > cv || (vv.w == cv && p3i < cpos)) ? 1 : 0;
    }
    if (rank < 16) {
        A[W0V + rank] = cv;
        A[W0P + rank] = __int_as_float(cpos);
        A[288 + cpos] = 1.0f;                 // mask flag
    }
    {
        float4 f = *(const float4*)&A[288 + lane*4];
        p[0] = (f.x != 0.f) ? 0.f : p[0];
        p[1] = (f.y != 0.f) ? 0.f : p[1];
        p[2] = (f.z != 0.f) ? 0.f : p[2];
        p[3] = (f.w != 0.f) ? 0.f : p[3];
    }
    *(float4*)&A[lane*4 + 4*(lane>>4)] = make_float4(p[0], p[1], p[2], p[3]);

    // ======== early lvl1 child table + K prefetch (hidden under stage C) ==
    float kr1[16];
    float pscoreD;
    {
        const int kp = lane >> 2, ci = lane & 3;
        pscoreD = A[W0V + kp];
        const int spos = __float_as_int(A[W0P + kp]);
        const int g1 = child32(spos, ci);
        A[GT + lane] = __int_as_float(g1);
        const float* kv = KV1h + (size_t)g1*32;
        #pragma unroll
        for (int i = 0; i < 4; ++i) *(float4*)&kr1[i*4] = *(const float4*)(kv + i*4);
    }

    // ======== stage C: msg0 = masked-p . V0 ========
    {
        const int dd = lane & 15, chunk = lane >> 4;
        const float* vb = v0 + ((size_t)(b*128 + n*16 + dd))*256 + chunk*64;
        float acc = 0.f;
        #pragma unroll
        for (int jj = 0; jj < 16; ++jj) {
            float4 vv = *(const float4*)(vb + jj*4);
            float4 pp = *(const float4*)&A[chunk*68 + jj*4];
            acc = fmaf(pp.x, vv.x, acc);
            acc = fmaf(pp.y, vv.y, acc);
            acc = fmaf(pp.z, vv.z, acc);
            acc = fmaf(pp.w, vv.w, acc);
        }
        acc += __shfl_xor(acc, 16);
        acc += __shfl_xor(acc, 32);
        if (lane < 16) A[MSG0 + dd] = acc;
    }

    // ======== stage D: lvl1 scoring (kr1 preloaded) + top-8 ========
    {
        #pragma unroll
        for (int t = 0; t < 4; ++t) {
            const int qtok = ((2*H0 + (t>>1)) << 5) + 2*W0 + (t&1);
            float sc = dot16(Q1hh + qtok*16, kr1) * 0.25f;
            const float mm = quadmax4(sc);
            const float e  = expf(sc - mm);
            const float su = quadsum4(e);
            A[288 + t*68 + lane] = (e / su) * pscoreD;
        }
    }
    {
        const int tg = lane >> 4;
        float v0r, v1r, v2r, v3r;
        {
            float4 t4 = *(const float4*)&A[288 + tg*68 + li*4];
            v0r = t4.x; v1r = t4.y; v2r = t4.z; v3r = t4.w;
        }
        float cv1 = 0.f; int cs1 = 0;
        #pragma unroll 1
        for (int it = 0; it < 8; ++it) {
            float bv = fmaxf(fmaxf(v0r, v1r), fmaxf(v2r, v3r));
            bv = rowmax16(bv);
            int cs = 0x7FFFFFFF;
            cs = (v3r == bv) ? (li*4 + 3) : cs;
            cs = (v2r == bv) ? (li*4 + 2) : cs;
            cs = (v1r == bv) ? (li*4 + 1) : cs;
            cs = (v0r == bv) ? (li*4 + 0) : cs;
            cs = rowmin16i(cs);
            v0r = (cs == li*4 + 0) ? 0.f : v0r;
            v1r = (cs == li*4 + 1) ? 0.f : v1r;
            v2r = (cs == li*4 + 2) ? 0.f : v2r;
            v3r = (cs == li*4 + 3) ? 0.f : v3r;
            if (li == it) { cv1 = bv; cs1 = cs; }
        }
        *(float4*)&A[288 + tg*68 + li*4] = make_float4(v0r, v1r, v2r, v3r);  // masked
        if (li < 8) {
            A[W1V + tg*8 + li] = cv1;
            A[W1P + tg*8 + li] = A[GT + cs1];   // g1 of winner key
        }
    }

    // ======== stage E: msg1 (V from global KV1, ids from GT[0..63]) ======
    {
        const int ks = lane >> 4, t2 = (lane >> 2) & 3, dq = lane & 3;
        float4 acc = make_float4(0.f, 0.f, 0.f, 0.f);
        #pragma unroll
        for (int jj = 0; jj < 4; ++jj) {
            float4 pv = *(const float4*)&A[288 + t2*68 + ks*16 + jj*4];
            const float pa[4] = {pv.x, pv.y, pv.z, pv.w};
            #pragma unroll
            for (int c = 0; c < 4; ++c) {
                const int g = __float_as_int(A[GT + ks*16 + jj*4 + c]);
                float4 vv = *(const float4*)(KV1h + (size_t)g*32 + 16 + dq*4);
                acc.x = fmaf(pa[c], vv.x, acc.x);
                acc.y = fmaf(pa[c], vv.y, acc.y);
                acc.z = fmaf(pa[c], vv.z, acc.z);
                acc.w = fmaf(pa[c], vv.w, acc.w);
            }
        }
        acc.x += __shfl_xor(acc.x, 16); acc.y += __shfl_xor(acc.y, 16);
        acc.z += __shfl_xor(acc.z, 16); acc.w += __shfl_xor(acc.w, 16);
        acc.x += __shfl_xor(acc.x, 32); acc.y += __shfl_xor(acc.y, 32);
        acc.z += __shfl_xor(acc.z, 32); acc.w += __shfl_xor(acc.w, 32);
        if (lane < 16)
            *(float4*)&A[MSG1 + t2*16 + dq*4] = acc;
    }

    // ======== stage F: lvl2, all 4 parents ========
    // child table for all 128 (parent,child) entries up front
    {
        const int t1h = lane >> 5, kk = lane & 31;
        const int kp2 = kk >> 2, ci2 = kk & 3;
        const int gA = child64(__float_as_int(A[W1P + t1h*8 + kp2]), ci2);
        const int gB = child64(__float_as_int(A[W1P + (2+t1h)*8 + kp2]), ci2);
        A[GT + t1h*32 + kk]     = __int_as_float(gA);
        A[GT + (2+t1h)*32 + kk] = __int_as_float(gB);
        const float psA = A[W1V + t1h*8 + kp2];
        const float psB = A[W1V + (2+t1h)*8 + kp2];

        // score pass 0: parents t1 = t1h (score base t1h*144)
        {
            const float* kv = KV2h + (size_t)gA*32;
            float kr[16];
            #pragma unroll
            for (int i = 0; i < 4; ++i) *(float4*)&kr[i*4] = *(const float4*)(kv + i*4);
            const int t1 = t1h;
            const int y1 = 2*H0 + (t1 >> 1), x1 = 2*W0 + (t1 & 1);
            #pragma unroll
            for (int t2 = 0; t2 < 4; ++t2) {
                const int qtok2 = ((2*y1 + (t2>>1)) << 6) + 2*x1 + (t2&1);
                float sc = dot16(Q2hh + qtok2*16, kr) * 0.25f;
                const float mm = quadmax4(sc);
                const float e  = expf(sc - mm);
                const float su = quadsum4(e);
                A[t1h*144 + t2*36 + kk] = (e / su) * psA;
            }
        }
        // score pass 1: parents t1 = 2 + t1h (score base 288 + t1h*144)
        {
            const float* kv = KV2h + (size_t)gB*32;
            float kr[16];
            #pragma unroll
            for (int i = 0; i < 4; ++i) *(float4*)&kr[i*4] = *(const float4*)(kv + i*4);
            const int t1 = 2 + t1h;
            const int y1 = 2*H0 + (t1 >> 1), x1 = 2*W0 + (t1 & 1);
            #pragma unroll
            for (int t2 = 0; t2 < 4; ++t2) {
                const int qtok2 = ((2*y1 + (t2>>1)) << 6) + 2*x1 + (t2&1);
                float sc = dot16(Q2hh + qtok2*16, kr) * 0.25f;
                const float mm = quadmax4(sc);
                const float e  = expf(sc - mm);
                const float su = quadsum4(e);
                A[288 + t1h*144 + t2*36 + kk] = (e / su) * psB;
            }
        }
    }
    // msg: both halves against stable scores/GT (unrolled -> one V wall)
    #pragma unroll
    for (int h = 0; h < 2; ++h) {
        const int ks2 = lane >> 5, qq = (lane >> 2) & 7, dq = lane & 3;
        const int t1l = qq >> 2, t2 = qq & 3;
        const int t1 = h*2 + t1l;
        const int sb = (t1 >> 1)*288 + (t1 & 1)*144 + t2*36;
        float4 acc = make_float4(0.f, 0.f, 0.f, 0.f);
        #pragma unroll
        for (int j4 = 0; j4 < 4; ++j4) {
            float4 pv = *(const float4*)&A[sb + ks2*16 + j4*4];
            const float pa[4] = {pv.x, pv.y, pv.z, pv.w};
            #pragma unroll
            for (int c = 0; c < 4; ++c) {
                const int g2 = __float_as_int(A[GT + t1*32 + ks2*16 + j4*4 + c]);
                float4 vv = *(const float4*)(KV2h + (size_t)g2*32 + 16 + dq*4);
                acc.x = fmaf(pa[c], vv.x, acc.x);
                acc.y = fmaf(pa[c], vv.y, acc.y);
                acc.z = fmaf(pa[c], vv.z, acc.z);
                acc.w = fmaf(pa[c], vv.w, acc.w);
            }
        }
        acc.x += __shfl_xor(acc.x, 32); acc.y += __shfl_xor(acc.y, 32);
        acc.z += __shfl_xor(acc.z, 32); acc.w += __shfl_xor(acc.w, 32);
        if (lane < 32) {
            float4 m1 = *(const float4*)&A[MSG1 + t1*16 + dq*4];
            float4 m0 = *(const float4*)&A[MSG0 + dq*4];
            acc.x += m1.x + m0.x;
            acc.y += m1.y + m0.y;
            acc.z += m1.z + m0.z;
            acc.w += m1.w + m0.w;
            *(float4*)&A[OUTT + (t1*4 + t2)*16 + dq*4] = acc;
        }
    }

    // ======== output: channel-major 4x4 patch ========
    {
        const int y = lane & 3, dd = lane >> 2;
        float vr[4];
        #pragma unroll
        for (int x = 0; x < 4; ++x) {
            const int t1 = (((y>>1) << 1) | (x>>1));
            const int t2 = (((y&1)  << 1) | (x&1));
            vr[x] = A[OUTT + (t1*4 + t2)*16 + dd];
        }
        float* op = out + (((size_t)(b*128 + n*16 + dd)*64 + 4*H0 + y))*64 + 4*W0;
        *(float4*)op = make_float4(vr[0], vr[1], vr[2], vr[3]);
    }
}

extern "C" void kernel_launch(void* const* d_in, const int* in_sizes, int n_in,
                              void* d_out, int out_size, void* d_ws, size_t ws_size,
                              hipStream_t stream)
{
    const float* q0 = (const float*)d_in[0];
    const float* k0 = (const float*)d_in[1];
    const float* v0 = (const float*)d_in[2];
    const float* q1 = (const float*)d_in[3];
    const float* k1 = (const float*)d_in[4];
    const float* v1 = (const float*)d_in[5];
    const float* q2 = (const float*)d_in[6];
    const float* k2 = (const float*)d_in[7];
    const float* v2 = (const float*)d_in[8];

    float* ws  = (float*)d_ws;
    float* Q1h = ws;                 // 4*8*1024*16 = 524288
    float* KV1 = ws + 524288;        // 4*8*1024*32 = 1048576
    float* Q2h = ws + 1572864;       // 4*8*4096*16 = 2097152
    float* KV2 = ws + 3670016;       // 4*8*4096*32 = 4194304

    k_repack<<<dim3(60, 8, 4), 256, 0, stream>>>(q1, k1, v1, q2, k2, v2,
                                                 Q1h, KV1, Q2h, KV2);
    k_fused<<<dim3(2048, 1, 1), 256, 0, stream>>>(q0, k0, v0,
                                                  Q1h, KV1, Q2h, KV2,
                                                  (float*)d_out);
}

// Round 9
// 156.355 us; speedup vs baseline: 1.0604x; 1.0604x over previous
//
#include <hip/hip_runtime.h>
#include <cstddef>

// QuadTree attention, 3 levels. B=4, C=128, NHEAD=8, d=16.
// Grids: 16x16 (S=256), 32x32 (S=1024), 64x64 (S=4096). TOPKS=(16,8,8).
//
// R9: two subtrees (adjacent cells l0=2L, 2L+1; same b,n) per wave,
// stage-interleaved (unrolled u-loops) so every gather wall has an
// independent twin context; K/V tile loads of lvl0 shared across the two
// contexts; q loads float2. XCD swizzle id&7=(b<<1)|nh keeps per-XCD KV
// working set (~2.7MB) inside the 4MB XCD L2.

#define DPP_QUAD_X1 0xB1
#define DPP_QUAD_X2 0x4E
#define DPP_ROR_1   0x121
#define DPP_ROR_2   0x122
#define DPP_ROR_4   0x124
#define DPP_ROR_8   0x128

template<int C>
__device__ __forceinline__ int dpp_i(int x) {
    return __builtin_amdgcn_mov_dpp(x, C, 0xF, 0xF, true);
}
template<int C>
__device__ __forceinline__ float dpp_f(float x) {
    return __int_as_float(__builtin_amdgcn_mov_dpp(__float_as_int(x), C, 0xF, 0xF, true));
}
__device__ __forceinline__ float rowmax16(float x) {
    x = fmaxf(x, dpp_f<DPP_ROR_1>(x));
    x = fmaxf(x, dpp_f<DPP_ROR_2>(x));
    x = fmaxf(x, dpp_f<DPP_ROR_4>(x));
    x = fmaxf(x, dpp_f<DPP_ROR_8>(x));
    return x;
}
__device__ __forceinline__ int rowmin16i(int x) {
    { int o = dpp_i<DPP_ROR_1>(x); x = o < x ? o : x; }
    { int o = dpp_i<DPP_ROR_2>(x); x = o < x ? o : x; }
    { int o = dpp_i<DPP_ROR_4>(x); x = o < x ? o : x; }
    { int o = dpp_i<DPP_ROR_8>(x); x = o < x ? o : x; }
    return x;
}
__device__ __forceinline__ float quadmax4(float x) {
    x = fmaxf(x, dpp_f<DPP_QUAD_X1>(x));
    x = fmaxf(x, dpp_f<DPP_QUAD_X2>(x));
    return x;
}
__device__ __forceinline__ float quadsum4(float x) {
    x += dpp_f<DPP_QUAD_X1>(x);
    x += dpp_f<DPP_QUAD_X2>(x);
    return x;
}
__device__ __forceinline__ float wavemax(float x) {
    x = rowmax16(x);
    x = fmaxf(x, __shfl_xor(x, 16));
    x = fmaxf(x, __shfl_xor(x, 32));
    return x;
}
__device__ __forceinline__ float wavesum(float x) {
    x += dpp_f<DPP_ROR_1>(x); x += dpp_f<DPP_ROR_2>(x);
    x += dpp_f<DPP_ROR_4>(x); x += dpp_f<DPP_ROR_8>(x);
    x += __shfl_xor(x, 16);   x += __shfl_xor(x, 32);
    return x;
}
__device__ __forceinline__ float dot16(const float* __restrict__ qp, const float* kr) {
    float s = 0.f;
    #pragma unroll
    for (int i = 0; i < 4; ++i) {
        float4 a = *(const float4*)(qp + i*4);
        s = fmaf(a.x, kr[i*4+0], s);
        s = fmaf(a.y, kr[i*4+1], s);
        s = fmaf(a.z, kr[i*4+2], s);
        s = fmaf(a.w, kr[i*4+3], s);
    }
    return s;
}
__device__ __forceinline__ int child32(int s, int c) {
    return (((s >> 4)*2 + (c >> 1)) << 5) + ((s & 15)*2 + (c & 1));
}
__device__ __forceinline__ int child64(int g, int c) {
    return (((g >> 5)*2 + (c >> 1)) << 6) + ((g & 31)*2 + (c & 1));
}

// per-context arena layout (floats)
#define W0V  560
#define W0P  576
#define MSG0 592
#define MSG1 608
#define W1V  672
#define W1P  704
#define GT   736
#define OUTT 864
#define ARENA 1120

// ---------------- Repack: head-major Q + KV-interleaved ----------------
__global__ __launch_bounds__(256) void k_repack(
    const float* __restrict__ q1, const float* __restrict__ k1, const float* __restrict__ v1,
    const float* __restrict__ q2, const float* __restrict__ k2, const float* __restrict__ v2,
    float* __restrict__ Q1h, float* __restrict__ KV1,
    float* __restrict__ Q2h, float* __restrict__ KV2)
{
    const int x = blockIdx.x, n = blockIdx.y, b = blockIdx.z;
    const int t = threadIdx.x;
    __shared__ float tA[16][129];
    __shared__ float tB[16][129];

    if (x < 20) {
        const float* src; float* dst; int S, ck;
        if (x < 4) { src = q1; dst = Q1h; S = 1024; ck = x; }
        else       { src = q2; dst = Q2h; S = 4096; ck = x - 4; }
        const int tok0 = ck * 256;
        const float* sp = src + ((size_t)(b*128 + n*16))*S + tok0;
        const int col = t & 127, half = t >> 7;
        #pragma unroll
        for (int j = 0; j < 8; ++j) {
            const int row = j*2 + half;
            tA[row][col] = sp[(size_t)row*S + col];
            tB[row][col] = sp[(size_t)row*S + col + 128];
        }
        __syncthreads();
        float* dp = dst + ((size_t)((b*8 + n)*S) + tok0 + t)*16;
        #pragma unroll
        for (int i = 0; i < 4; ++i) {
            float4 o;
            o.x = (half ? tB : tA)[i*4+0][col];
            o.y = (half ? tB : tA)[i*4+1][col];
            o.z = (half ? tB : tA)[i*4+2][col];
            o.w = (half ? tB : tA)[i*4+3][col];
            *(float4*)(dp + i*4) = o;
        }
    } else {
        const float* sK; const float* sV; float* dst; int S, ck;
        if (x < 28) { sK = k1; sV = v1; dst = KV1; S = 1024; ck = x - 20; }
        else        { sK = k2; sV = v2; dst = KV2; S = 4096; ck = x - 28; }
        const int tok0 = ck * 128;
        const int col = t & 127, rp = t >> 7;
        const float* kp = sK + ((size_t)(b*128 + n*16))*S + tok0;
        const float* vp = sV + ((size_t)(b*128 + n*16))*S + tok0;
        #pragma unroll
        for (int j = 0; j < 8; ++j) {
            const int row = j*2 + rp;
            tA[row][col] = kp[(size_t)row*S + col];
            tB[row][col] = vp[(size_t)row*S + col];
        }
        __syncthreads();
        const int tok = t >> 1, half = t & 1;
        float* dp = dst + (((size_t)((b*8 + n)*S) + tok0 + tok))*32 + half*16;
        #pragma unroll
        for (int i = 0; i < 4; ++i) {
            float4 o;
            o.x = (half ? tB : tA)[i*4+0][tok];
            o.y = (half ? tB : tA)[i*4+1][tok];
            o.z = (half ? tB : tA)[i*4+2][tok];
            o.w = (half ? tB : tA)[i*4+3][tok];
            *(float4*)(dp + i*4) = o;
        }
    }
}

// ---------------- Fused 3-level subtree kernel, 2 subtrees/wave ---------
// grid (1024,1,1) x 256. id = (lpair<<3) | (b<<1) | nh.
__global__ __launch_bounds__(256, 4) void k_fused(
    const float* __restrict__ q0, const float* __restrict__ k0, const float* __restrict__ v0,
    const float* __restrict__ Q1h, const float* __restrict__ KV1,
    const float* __restrict__ Q2h, const float* __restrict__ KV2,
    float* __restrict__ out)
{
    const int tid = threadIdx.x, lane = tid & 63, wid = tid >> 6;
    const int id    = blockIdx.x;
    const int nh    = id & 1;
    const int b     = (id >> 1) & 3;
    const int lpair = id >> 3;               // 0..127
    const int n     = nh*4 + wid;
    const int l0b   = lpair*2;               // even
    const int H0 = l0b >> 4, W0b = l0b & 15; // both contexts share H0; W0u=W0b+u

    __shared__ float arenaAll[4][2][ARENA];
    float* const A0 = arenaAll[wid][0];
    float* const A1 = arenaAll[wid][1];

    const float* Q1hh = Q1h + (size_t)((b*8 + n)*1024)*16;
    const float* KV1h = KV1 + (size_t)((b*8 + n)*1024)*32;
    const float* Q2hh = Q2h + (size_t)((b*8 + n)*4096)*16;
    const float* KV2h = KV2 + (size_t)((b*8 + n)*4096)*32;

    // ======== stage A: lvl0 scores, K shared, q as float2 ========
    const float* qb = q0 + ((size_t)(b*128 + n*16))*256 + l0b;
    const float* kb = k0 + ((size_t)(b*128 + n*16))*256 + lane*4;
    float2 q2r[16];
    #pragma unroll
    for (int dd = 0; dd < 16; ++dd) q2r[dd] = *(const float2*)(qb + (size_t)dd*256);
    float pA[4] = {0.f,0.f,0.f,0.f}, pB[4] = {0.f,0.f,0.f,0.f};
    #pragma unroll
    for (int dd = 0; dd < 16; ++dd) {
        float4 kv = *(const float4*)(kb + (size_t)dd*256);
        pA[0] = fmaf(q2r[dd].x, kv.x, pA[0]);
        pA[1] = fmaf(q2r[dd].x, kv.y, pA[1]);
        pA[2] = fmaf(q2r[dd].x, kv.z, pA[2]);
        pA[3] = fmaf(q2r[dd].x, kv.w, pA[3]);
        pB[0] = fmaf(q2r[dd].y, kv.x, pB[0]);
        pB[1] = fmaf(q2r[dd].y, kv.y, pB[1]);
        pB[2] = fmaf(q2r[dd].y, kv.z, pB[2]);
        pB[3] = fmaf(q2r[dd].y, kv.w, pB[3]);
    }
    #pragma unroll
    for (int j = 0; j < 4; ++j) { pA[j] *= 0.25f; pB[j] *= 0.25f; }
    float mA = fmaxf(fmaxf(pA[0], pA[1]), fmaxf(pA[2], pA[3]));
    float mB = fmaxf(fmaxf(pB[0], pB[1]), fmaxf(pB[2], pB[3]));
    mA = wavemax(mA); mB = wavemax(mB);
    float lsA = 0.f, lsB = 0.f;
    #pragma unroll
    for (int j = 0; j < 4; ++j) {
        pA[j] = expf(pA[j] - mA); lsA += pA[j];
        pB[j] = expf(pB[j] - mB); lsB += pB[j];
    }
    const float invA = 1.f / wavesum(lsA);
    const float invB = 1.f / wavesum(lsB);
    #pragma unroll
    for (int j = 0; j < 4; ++j) { pA[j] *= invA; pB[j] *= invB; }

    const int li = lane & 15;

    // ======== stage B: top-16 of 256, both contexts interleaved ========
    float w[2][4];
    #pragma unroll
    for (int j = 0; j < 4; ++j) { w[0][j] = pA[j]; w[1][j] = pB[j]; }
    float cv[2] = {0.f, 0.f}; int cpos[2] = {0, 0};
    #pragma unroll 1
    for (int it = 0; it < 16; ++it) {
        #pragma unroll
        for (int u = 0; u < 2; ++u) {
            float bv = fmaxf(fmaxf(w[u][0], w[u][1]), fmaxf(w[u][2], w[u][3]));
            bv = rowmax16(bv);
            int cs = 0x7FFFFFFF;
            cs = (w[u][3] == bv) ? (lane*4 + 3) : cs;
            cs = (w[u][2] == bv) ? (lane*4 + 2) : cs;
            cs = (w[u][1] == bv) ? (lane*4 + 1) : cs;
            cs = (w[u][0] == bv) ? (lane*4 + 0) : cs;
            cs = rowmin16i(cs);
            w[u][0] = (cs == lane*4 + 0) ? 0.f : w[u][0];
            w[u][1] = (cs == lane*4 + 1) ? 0.f : w[u][1];
            w[u][2] = (cs == lane*4 + 2) ? 0.f : w[u][2];
            w[u][3] = (cs == lane*4 + 3) ? 0.f : w[u][3];
            if (li == it) { cv[u] = bv; cpos[u] = cs; }
        }
    }
    // rank merge per context
    #pragma unroll
    for (int u = 0; u < 2; ++u) {
        float* A = u ? A1 : A0;
        A[lane]      = cv[u];
        A[64 + lane] = __int_as_float(cpos[u]);
        *(float4*)&A[288 + lane*4] = make_float4(0.f, 0.f, 0.f, 0.f);
    }
    #pragma unroll
    for (int u = 0; u < 2; ++u) {
        float* A = u ? A1 : A0;
        const float cu = cv[u]; const int pu = cpos[u];
        int rank = 0;
        #pragma unroll
        for (int jj = 0; jj < 16; ++jj) {
            float4 vv = *(const float4*)&A[jj*4];
            float4 pw = *(const float4*)&A[64 + jj*4];
            const int p0i = __float_as_int(pw.x), p1i = __float_as_int(pw.y);
            const int p2i = __float_as_int(pw.z), p3i = __float_as_int(pw.w);
            rank += (vv.x > cu || (vv.x == cu && p0i < pu)) ? 1 : 0;
            rank += (vv.y > cu || (vv.y == cu && p1i < pu)) ? 1 : 0;
            rank += (vv.z > cu || (vv.z == cu && p2i < pu)) ? 1 : 0;
            rank += (vv.w > cu || (vv.w == cu && p3i < pu)) ? 1 : 0;
        }
        if (rank < 16) {
            A[W0V + rank] = cu;
            A[W0P + rank] = __int_as_float(pu);
            A[288 + pu]   = 1.0f;
        }
    }
    {   // apply masks + padded store
        float4 fA = *(const float4*)&A0[288 + lane*4];
        float4 fB = *(const float4*)&A1[288 + lane*4];
        pA[0] = (fA.x != 0.f) ? 0.f : pA[0];
        pA[1] = (fA.y != 0.f) ? 0.f : pA[1];
        pA[2] = (fA.z != 0.f) ? 0.f : pA[2];
        pA[3] = (fA.w != 0.f) ? 0.f : pA[3];
        pB[0] = (fB.x != 0.f) ? 0.f : pB[0];
        pB[1] = (fB.y != 0.f) ? 0.f : pB[1];
        pB[2] = (fB.z != 0.f) ? 0.f : pB[2];
        pB[3] = (fB.w != 0.f) ? 0.f : pB[3];
        const int pad = lane*4 + 4*(lane>>4);
        *(float4*)&A0[pad] = make_float4(pA[0], pA[1], pA[2], pA[3]);
        *(float4*)&A1[pad] = make_float4(pB[0], pB[1], pB[2], pB[3]);
    }

    // ======== early lvl1 child table + K prefetch (both contexts) ========
    float kr1[2][16];
    float psD[2];
    {
        const int kp = lane >> 2, ci = lane & 3;
        #pragma unroll
        for (int u = 0; u < 2; ++u) {
            float* A = u ? A1 : A0;
            psD[u] = A[W0V + kp];
            const int spos = __float_as_int(A[W0P + kp]);
            const int g1 = child32(spos, ci);
            A[GT + lane] = __int_as_float(g1);
            const float* kv = KV1h + (size_t)g1*32;
            #pragma unroll
            for (int i = 0; i < 4; ++i) *(float4*)&kr1[u][i*4] = *(const float4*)(kv + i*4);
        }
    }

    // ======== stage C: msg0, V loads shared across contexts ========
    {
        const int dd = lane & 15, chunk = lane >> 4;
        const float* vb = v0 + ((size_t)(b*128 + n*16 + dd))*256 + chunk*64;
        float a0 = 0.f, a1 = 0.f;
        #pragma unroll
        for (int jj = 0; jj < 16; ++jj) {
            float4 vv = *(const float4*)(vb + jj*4);
            float4 p0 = *(const float4*)&A0[chunk*68 + jj*4];
            float4 p1 = *(const float4*)&A1[chunk*68 + jj*4];
            a0 = fmaf(p0.x, vv.x, a0); a0 = fmaf(p0.y, vv.y, a0);
            a0 = fmaf(p0.z, vv.z, a0); a0 = fmaf(p0.w, vv.w, a0);
            a1 = fmaf(p1.x, vv.x, a1); a1 = fmaf(p1.y, vv.y, a1);
            a1 = fmaf(p1.z, vv.z, a1); a1 = fmaf(p1.w, vv.w, a1);
        }
        a0 += __shfl_xor(a0, 16); a0 += __shfl_xor(a0, 32);
        a1 += __shfl_xor(a1, 16); a1 += __shfl_xor(a1, 32);
        if (lane < 16) { A0[MSG0 + dd] = a0; A1[MSG0 + dd] = a1; }
    }

    // ======== stage D: lvl1 scoring (kr1 preloaded) + top-8 ========
    #pragma unroll
    for (int u = 0; u < 2; ++u) {
        float* A = u ? A1 : A0;
        const int W0u = W0b + u;
        #pragma unroll
        for (int t = 0; t < 4; ++t) {
            const int qtok = ((2*H0 + (t>>1)) << 5) + 2*W0u + (t&1);
            float sc = dot16(Q1hh + qtok*16, kr1[u]) * 0.25f;
            const float mm = quadmax4(sc);
            const float e  = expf(sc - mm);
            const float su = quadsum4(e);
            A[288 + t*68 + lane] = (e / su) * psD[u];
        }
    }
    {
        const int tg = lane >> 4;
        float r[2][4];
        {
            float4 t0 = *(const float4*)&A0[288 + tg*68 + li*4];
            float4 t1 = *(const float4*)&A1[288 + tg*68 + li*4];
            r[0][0] = t0.x; r[0][1] = t0.y; r[0][2] = t0.z; r[0][3] = t0.w;
            r[1][0] = t1.x; r[1][1] = t1.y; r[1][2] = t1.z; r[1][3] = t1.w;
        }
        float cv1[2] = {0.f, 0.f}; int cs1[2] = {0, 0};
        #pragma unroll 1
        for (int it = 0; it < 8; ++it) {
            #pragma unroll
            for (int u = 0; u < 2; ++u) {
                float bv = fmaxf(fmaxf(r[u][0], r[u][1]), fmaxf(r[u][2], r[u][3]));
                bv = rowmax16(bv);
                int cs = 0x7FFFFFFF;
                cs = (r[u][3] == bv) ? (li*4 + 3) : cs;
                cs = (r[u][2] == bv) ? (li*4 + 2) : cs;
                cs = (r[u][1] == bv) ? (li*4 + 1) : cs;
                cs = (r[u][0] == bv) ? (li*4 + 0) : cs;
                cs = rowmin16i(cs);
                r[u][0] = (cs == li*4 + 0) ? 0.f : r[u][0];
                r[u][1] = (cs == li*4 + 1) ? 0.f : r[u][1];
                r[u][2] = (cs == li*4 + 2) ? 0.f : r[u][2];
                r[u][3] = (cs == li*4 + 3) ? 0.f : r[u][3];
                if (li == it) { cv1[u] = bv; cs1[u] = cs; }
            }
        }
        #pragma unroll
        for (int u = 0; u < 2; ++u) {
            float* A = u ? A1 : A0;
            *(float4*)&A[288 + tg*68 + li*4] =
                make_float4(r[u][0], r[u][1], r[u][2], r[u][3]);
            if (li < 8) {
                A[W1V + tg*8 + li] = cv1[u];
                A[W1P + tg*8 + li] = A[GT + cs1[u]];
            }
        }
    }

    // ======== stage E: msg1 per context ========
    {
        const int ks = lane >> 4, t2 = (lane >> 2) & 3, dq = lane & 3;
        #pragma unroll
        for (int u = 0; u < 2; ++u) {
            float* A = u ? A1 : A0;
            float4 acc = make_float4(0.f, 0.f, 0.f, 0.f);
            #pragma unroll
            for (int jj = 0; jj < 4; ++jj) {
                float4 pv = *(const float4*)&A[288 + t2*68 + ks*16 + jj*4];
                const float pa[4] = {pv.x, pv.y, pv.z, pv.w};
                #pragma unroll
                for (int c = 0; c < 4; ++c) {
                    const int g = __float_as_int(A[GT + ks*16 + jj*4 + c]);
                    float4 vv = *(const float4*)(KV1h + (size_t)g*32 + 16 + dq*4);
                    acc.x = fmaf(pa[c], vv.x, acc.x);
                    acc.y = fmaf(pa[c], vv.y, acc.y);
                    acc.z = fmaf(pa[c], vv.z, acc.z);
                    acc.w = fmaf(pa[c], vv.w, acc.w);
                }
            }
            acc.x += __shfl_xor(acc.x, 16); acc.y += __shfl_xor(acc.y, 16);
            acc.z += __shfl_xor(acc.z, 16); acc.w += __shfl_xor(acc.w, 16);
            acc.x += __shfl_xor(acc.x, 32); acc.y += __shfl_xor(acc.y, 32);
            acc.z += __shfl_xor(acc.z, 32); acc.w += __shfl_xor(acc.w, 32);
            if (lane < 16)
                *(float4*)&A[MSG1 + t2*16 + dq*4] = acc;
        }
    }

    // ======== stage F: lvl2 ========
    {
        const int t1h = lane >> 5, kk = lane & 31;
        const int kp2 = kk >> 2, ci2 = kk & 3;
        float krA[2][16], krB[2][16];
        float psA[2], psB[2];
        // GT fill + all K loads up front (one wall)
        #pragma unroll
        for (int u = 0; u < 2; ++u) {
            float* A = u ? A1 : A0;
            const int gA = child64(__float_as_int(A[W1P + t1h*8 + kp2]), ci2);
            const int gB = child64(__float_as_int(A[W1P + (2+t1h)*8 + kp2]), ci2);
            A[GT + t1h*32 + kk]     = __int_as_float(gA);
            A[GT + (2+t1h)*32 + kk] = __int_as_float(gB);
            psA[u] = A[W1V + t1h*8 + kp2];
            psB[u] = A[W1V + (2+t1h)*8 + kp2];
            const float* kva = KV2h + (size_t)gA*32;
            const float* kvb = KV2h + (size_t)gB*32;
            #pragma unroll
            for (int i = 0; i < 4; ++i) {
                *(float4*)&krA[u][i*4] = *(const float4*)(kva + i*4);
                *(float4*)&krB[u][i*4] = *(const float4*)(kvb + i*4);
            }
        }
        // score pass 0 (t1 = t1h) and pass 1 (t1 = 2+t1h) per context
        #pragma unroll
        for (int u = 0; u < 2; ++u) {
            float* A = u ? A1 : A0;
            const int W0u = W0b + u;
            {
                const int t1 = t1h;
                const int y1 = 2*H0 + (t1 >> 1), x1 = 2*W0u + (t1 & 1);
                #pragma unroll
                for (int t2 = 0; t2 < 4; ++t2) {
                    const int qtok2 = ((2*y1 + (t2>>1)) << 6) + 2*x1 + (t2&1);
                    float sc = dot16(Q2hh + qtok2*16, krA[u]) * 0.25f;
                    const float mm = quadmax4(sc);
                    const float e  = expf(sc - mm);
                    const float su = quadsum4(e);
                    A[t1h*144 + t2*36 + kk] = (e / su) * psA[u];
                }
            }
            {
                const int t1 = 2 + t1h;
                const int y1 = 2*H0 + (t1 >> 1), x1 = 2*W0u + (t1 & 1);
                #pragma unroll
                for (int t2 = 0; t2 < 4; ++t2) {
                    const int qtok2 = ((2*y1 + (t2>>1)) << 6) + 2*x1 + (t2&1);
                    float sc = dot16(Q2hh + qtok2*16, krB[u]) * 0.25f;
                    const float mm = quadmax4(sc);
                    const float e  = expf(sc - mm);
                    const float su = quadsum4(e);
                    A[288 + t1h*144 + t2*36 + kk] = (e / su) * psB[u];
                }
            }
        }
    }
    // msg halves per context
    {
        const int ks2 = lane >> 5, qq = (lane >> 2) & 7, dq = lane & 3;
        const int t1l = qq >> 2, t2 = qq & 3;
        #pragma unroll
        for (int u = 0; u < 2; ++u) {
            float* A = u ? A1 : A0;
            #pragma unroll
            for (int h = 0; h < 2; ++h) {
                const int t1 = h*2 + t1l;
                const int sb = (t1 >> 1)*288 + (t1 & 1)*144 + t2*36;
                float4 acc = make_float4(0.f, 0.f, 0.f, 0.f);
                #pragma unroll
                for (int j4 = 0; j4 < 4; ++j4) {
                    float4 pv = *(const float4*)&A[sb + ks2*16 + j4*4];
                    const float pa[4] = {pv.x, pv.y, pv.z, pv.w};
                    #pragma unroll
                    for (int c = 0; c < 4; ++c) {
                        const int g2 = __float_as_int(A[GT + t1*32 + ks2*16 + j4*4 + c]);
                        float4 vv = *(const float4*)(KV2h + (size_t)g2*32 + 16 + dq*4);
                        acc.x = fmaf(pa[c], vv.x, acc.x);
                        acc.y = fmaf(pa[c], vv.y, acc.y);
                        acc.z = fmaf(pa[c], vv.z, acc.z);
                        acc.w = fmaf(pa[c], vv.w, acc.w);
                    }
                }
                acc.x += __shfl_xor(acc.x, 32); acc.y += __shfl_xor(acc.y, 32);
                acc.z += __shfl_xor(acc.z, 32); acc.w += __shfl_xor(acc.w, 32);
                if (lane < 32) {
                    float4 m1 = *(const float4*)&A[MSG1 + t1*16 + dq*4];
                    float4 m0 = *(const float4*)&A[MSG0 + dq*4];
                    acc.x += m1.x + m0.x;
                    acc.y += m1.y + m0.y;
                    acc.z += m1.z + m0.z;
                    acc.w += m1.w + m0.w;
                    *(float4*)&A[OUTT + (t1*4 + t2)*16 + dq*4] = acc;
                }
            }
        }
    }

    // ======== output: two adjacent 4x4 patches (same rows) ========
    {
        const int y = lane & 3, dd = lane >> 2;
        #pragma unroll
        for (int u = 0; u < 2; ++u) {
            float* A = u ? A1 : A0;
            const int W0u = W0b + u;
            float vr[4];
            #pragma unroll
            for (int x = 0; x < 4; ++x) {
                const int t1 = (((y>>1) << 1) | (x>>1));
                const int t2 = (((y&1)  << 1) | (x&1));
                vr[x] = A[OUTT + (t1*4 + t2)*16 + dd];
            }
            float* op = out + (((size_t)(b*128 + n*16 + dd)*64 + 4*H0 + y))*64 + 4*W0u;
            *(float4*)op = make_float4(vr[0], vr[1], vr[2], vr[3]);
        }
    }
}

extern "C" void kernel_launch(void* const* d_in, const int* in_sizes, int n_in,
                              void* d_out, int out_size, void* d_ws, size_t ws_size,
                              hipStream_t stream)
{
    const float* q0 = (const float*)d_in[0];
    const float* k0 = (const float*)d_in[1];
    const float* v0 = (const float*)d_in[2];
    const float* q1 = (const float*)d_in[3];
    const float* k1 = (const float*)d_in[4];
    const float* v1 = (const float*)d_in[5];
    const float* q2 = (const float*)d_in[6];
    const float* k2 = (const float*)d_in[7];
    const float* v2 = (const float*)d_in[8];

    float* ws  = (float*)d_ws;
    float* Q1h = ws;                 // 4*8*1024*16 = 524288
    float* KV1 = ws + 524288;        // 4*8*1024*32 = 1048576
    float* Q2h = ws + 1572864;       // 4*8*4096*16 = 2097152
    float* KV2 = ws + 3670016;       // 4*8*4096*32 = 4194304

    k_repack<<<dim3(60, 8, 4), 256, 0, stream>>>(q1, k1, v1, q2, k2, v2,
                                                 Q1h, KV1, Q2h, KV2);
    k_fused<<<dim3(1024, 1, 1), 256, 0, stream>>>(q0, k0, v0,
                                                  Q1h, KV1, Q2h, KV2,
                                                  (float*)d_out);
}